// Round 4
// baseline (340.775 us; speedup 1.0000x reference)
//
#include <hip/hip_runtime.h>

#define NCH 12
#define NB  4
#define BC  48
#define HW0 (512 * 512)

// Gaussian 1-D weights (win=11, sigma=1.5), exact to f32 — computed offline.
#define GK_INIT { 0.00102840f, 0.00759863f, 0.03600078f, 0.10936081f, \
                  0.21300541f, 0.26601164f, 0.21300541f, 0.10936081f, \
                  0.03600078f, 0.00759863f, 0.00102840f }

// ---------------------------------------------------------------------------
// Prep: per-pixel softmax WITHOUT max-subtraction (|pred|<=~6 for N(0,1) ->
// no overflow). Writes X0 = softmax probs as bf16 (round-to-nearest) and
// Y0m = (1<<tgt) 12-bit class mask. Moves all exp/div work out of k_ssim0
// and shrinks its per-pixel halo to two u16 loads.
__global__ __launch_bounds__(256)
void k_prep(const float4* __restrict__ pred, const int4* __restrict__ tgt,
            ushort4* __restrict__ X0, ushort4* __restrict__ Y0m,
            double* __restrict__ acc) {
    if (blockIdx.x == 0) {
        for (int t = threadIdx.x; t < 480; t += 256) acc[t] = 0.0;
    }
    int i = blockIdx.x * blockDim.x + threadIdx.x;
    if (i >= NB * (HW0 / 4)) return;
    int b = i >> 16;                 // HW0/4 = 65536
    int p = i & 65535;
    const float4* base = pred + (((size_t)b * NCH) << 16) + p;
    float4 e[NCH];
    float4 s = make_float4(0.f, 0.f, 0.f, 0.f);
#pragma unroll
    for (int c = 0; c < NCH; ++c) {
        float4 v = base[(size_t)c << 16];
        e[c].x = __expf(v.x); e[c].y = __expf(v.y);
        e[c].z = __expf(v.z); e[c].w = __expf(v.w);
        s.x += e[c].x; s.y += e[c].y; s.z += e[c].z; s.w += e[c].w;
    }
    float4 u;
    u.x = 1.f / s.x; u.y = 1.f / s.y; u.z = 1.f / s.z; u.w = 1.f / s.w;
#pragma unroll
    for (int c = 0; c < NCH; ++c) {
        // bf16 round-to-nearest (values in [0,1], no inf/nan possible)
        unsigned ax = (__float_as_uint(e[c].x * u.x) + 0x8000u) >> 16;
        unsigned ay = (__float_as_uint(e[c].y * u.y) + 0x8000u) >> 16;
        unsigned az = (__float_as_uint(e[c].z * u.z) + 0x8000u) >> 16;
        unsigned aw = (__float_as_uint(e[c].w * u.w) + 0x8000u) >> 16;
        X0[(((size_t)b * NCH + c) << 16) + p] =
            make_ushort4((ushort)ax, (ushort)ay, (ushort)az, (ushort)aw);
    }
    int4 t4 = tgt[((size_t)b << 16) + p];
    Y0m[((size_t)b << 16) + p] =
        make_ushort4((ushort)(1u << t4.x), (ushort)(1u << t4.y),
                     (ushort)(1u << t4.z), (ushort)(1u << t4.w));
}

// ---------------------------------------------------------------------------
// Scale-0 SSIM. Halo reads 2 x u16 per pixel (bf16 prob + class mask) —
// no expf, no f32 mul, no third stream, and NO pooled-output epilogue
// (scales 1-4 pool X0 themselves). Otherwise the validated 250.8 µs
// structure (bf16 truncated moment pack, ballot y-bits).
__global__ __launch_bounds__(256, 8)
void k_ssim0(const ushort* __restrict__ X0, const ushort* __restrict__ Y0m,
             double* __restrict__ acc) {
    constexpr int SS = 43;
    constexpr int TS = 35;
    constexpr int H = 512, W = 512, OH = 502, OW = 502, tilesX = 16;
    __shared__ float sx[42 * SS + 4];
    __shared__ uint2 tm4[42 * TS];          // bf16 packed moments
    __shared__ unsigned long long ybits[30];
    __shared__ float red[8];

    const float gk[11] = GK_INIT;

    const int bc = blockIdx.y;
    const int tile = blockIdx.x;
    const int ty = tile / tilesX, tx = tile - ty * tilesX;
    const int oy = ty * 32, ox = tx * 32;
    const int tid = threadIdx.x;
    const bool interior = (oy + 41 < H) && (ox + 41 < W);

    const int b = bc / NCH, cls = bc - (bc / NCH) * NCH;
    const ushort* Xb = X0 + ((size_t)bc << 18);
    const ushort* Mb = Y0m + ((size_t)b << 18);

    // ---- halo load 42x42: bf16 x + class-mask bit; y bits via ballot
    {
        int r = tid / 42, c = tid - (tid / 42) * 42;
#pragma unroll
        for (int k = 0; k < 7; ++k) {
            bool inr = (k < 6) || (tid < 228);
            int gy = oy + r, gx = ox + c;
            bool ld = inr && (interior || (gy < H && gx < W));
            float xv = 0.f;
            bool bit = false;
            if (ld) {
                int off = gy * W + gx;
                xv = __uint_as_float((unsigned)Xb[off] << 16);
                bit = (Mb[off] >> cls) & 1;
            }
            unsigned long long mk = __ballot(bit);
            if ((tid & 63) == 0) ybits[(tid >> 6) + (k << 2)] = mk;
            if (inr) sx[r * SS + c] = xv;
            c += 4; r += 6;
            if (c >= 42) { c -= 42; r += 1; }
        }
        if (tid == 0) { ybits[28] = 0ull; ybits[29] = 0ull; }
    }
    __syncthreads();

    // ---- horizontal conv: 42 rows x 6 strips of 6 outputs (252 threads)
    if (tid < 252) {
        int rr = tid / 6, s = tid - (tid / 6) * 6;
        int c0 = s * 6;
        const float* px = sx + rr * SS + c0;
        float ac0[6] = {}, ac1[6] = {}, ac2[6] = {}, ac3[6] = {};
        unsigned long long win;
        {
            int i0 = rr * 42 + c0;
            int w = i0 >> 6, sh = i0 & 63;
            unsigned long long lo = ybits[w], hi = ybits[w + 1];
            win = sh ? ((lo >> sh) | (hi << (64 - sh))) : lo;
        }
#pragma unroll
        for (int j = 0; j < 16; ++j) {
            float xv = px[j];
            float xx = xv * xv;
            bool bit = (win >> j) & 1;
            float yv = bit ? 1.f : 0.f;
            float xy = bit ? xv : 0.f;
#pragma unroll
            for (int o = 0; o < 6; ++o) {
                int kk = j - o;
                if (kk >= 0 && kk <= 10) {
                    float g = gk[kk];
                    ac0[o] = fmaf(g, xv, ac0[o]);
                    ac1[o] = fmaf(g, yv, ac1[o]);
                    ac2[o] = fmaf(g, xx, ac2[o]);
                    ac3[o] = fmaf(g, xy, ac3[o]);
                }
            }
        }
        int ob = rr * TS + c0;
#pragma unroll
        for (int o = 0; o < 6; ++o) {
            if (c0 + o < 32) {
                unsigned ua = __float_as_uint(ac0[o]);
                unsigned ub = __float_as_uint(ac1[o]);
                unsigned uc = __float_as_uint(ac2[o]);
                unsigned ud = __float_as_uint(ac3[o]);
                tm4[ob + o] = make_uint2((ua >> 16) | (ub & 0xFFFF0000u),
                                         (uc >> 16) | (ud & 0xFFFF0000u));
            }
        }
    }
    __syncthreads();

    // ---- vertical conv + SSIM (unpack bf16 pairs)
    const float C1 = 1e-4f, C2 = 9e-4f;
    const int cc = tid & 31, rg = tid >> 5, r0 = rg << 2;
    float a0[4] = {}, a1[4] = {}, a2[4] = {}, a3[4] = {};
    const int vb = r0 * TS + cc;
#pragma unroll
    for (int k = 0; k < 14; ++k) {
        uint2 tv = tm4[vb + k * TS];
        float m1v = __uint_as_float(tv.x << 16);
        float m2v = __uint_as_float(tv.x & 0xFFFF0000u);
        float xxv = __uint_as_float(tv.y << 16);
        float xyv = __uint_as_float(tv.y & 0xFFFF0000u);
#pragma unroll
        for (int j = 0; j < 4; ++j) {
            int kk = k - j;
            if (kk >= 0 && kk <= 10) {
                float g = gk[kk];
                a0[j] = fmaf(g, m1v, a0[j]);
                a1[j] = fmaf(g, m2v, a1[j]);
                a2[j] = fmaf(g, xxv, a2[j]);
                a3[j] = fmaf(g, xyv, a3[j]);
            }
        }
    }
    float cs_l = 0.f, ss_l = 0.f;
    const bool colok = (ox + cc < OW);
#pragma unroll
    for (int j = 0; j < 4; ++j) {
        if (colok && (oy + r0 + j < OH)) {
            float m1 = a0[j], m2 = a1[j];
            float sxx = a2[j], sxy_ = a3[j];
            float m11 = m1 * m1, m22 = m2 * m2, m12 = m1 * m2;
            float v1 = sxx - m11, v2 = m2 - m22, cov = sxy_ - m12;  // y^2=y
            float d1 = m11 + m22 + C1, d2 = v1 + v2 + C2;
            float n2 = 2.f * cov + C2;
            float q = 1.f / (d1 * d2);
            cs_l = fmaf(n2 * d1, q, cs_l);
            ss_l = fmaf((2.f * m12 + C1) * n2, q, ss_l);
        }
    }

    // ---- block reduction
    for (int off = 32; off; off >>= 1) {
        cs_l += __shfl_down(cs_l, off);
        ss_l += __shfl_down(ss_l, off);
    }
    int wv = tid >> 6, ln = tid & 63;
    if (ln == 0) { red[wv] = cs_l; red[4 + wv] = ss_l; }
    __syncthreads();
    if (tid == 0) {
        double cs_b = (double)red[0] + (double)red[1] + (double)red[2] + (double)red[3];
        double ss_b = (double)red[4] + (double)red[5] + (double)red[6] + (double)red[7];
        atomicAdd(&acc[bc], cs_b);
        atomicAdd(&acc[48 + bc], ss_b);
    }
}

// ---------------------------------------------------------------------------
// Generic SSIM tile body for scales 1-4, sourcing X0 (bf16) / Y0m (mask)
// directly with inline SCxSC avg pooling (SC = 2,4,8,16). Pooled y-counts
// are exact ints; yv keeps the y*256 convention: count << (8-2*PIN).
// Structure identical to the round-1-validated tile body.
template <int PIN>
__device__ __forceinline__ void ssim_tile_b(
    const ushort* __restrict__ X0, const ushort* __restrict__ Y0m,
    int tile, int bc, double* __restrict__ acc,
    float* sx, uint2* tm4, ushort* tm5, ushort* syu, float* red) {
    constexpr int SS = 43;
    constexpr int TS = 35;
    constexpr int SC = 1 << PIN;
    constexpr int H = 512 >> PIN;           // level size (W == H)
    constexpr int OH = H - 10;
    constexpr int txs = (PIN == 1) ? 3 : (PIN == 2) ? 2 : (PIN == 3) ? 1 : 0;
    const float gk[11] = GK_INIT;

    const int ty = tile >> txs, tx = tile & ((1 << txs) - 1);
    const int oy = ty * 32, ox = tx * 32;
    const int tid = threadIdx.x;
    const bool interior = (oy + 41 < H) && (ox + 41 < H);

    const int b = bc / NCH, cls = bc - (bc / NCH) * NCH;
    const ushort* Xb = X0 + ((size_t)bc << 18);
    const ushort* Mb = Y0m + ((size_t)b << 18);

    // ---- halo load 42x42 with inline SCxSC pooling from the 512x512 plane
    {
        int r = tid / 42, c = tid - (tid / 42) * 42;
#pragma unroll
        for (int k = 0; k < 7; ++k) {
            bool inr = (k < 6) || (tid < 228);
            int gy = oy + r, gx = ox + c;
            bool ld = inr && (interior || (gy < H && gx < H));
            float xv = 0.f;
            ushort yv = 0;
            if (ld) {
                const ushort* qx = Xb + (SC * gy) * 512 + SC * gx;
                const ushort* qm = Mb + (SC * gy) * 512 + SC * gx;
                float s = 0.f; unsigned cnt = 0;
#pragma unroll
                for (int a = 0; a < SC; ++a) {
                    const ushort* qxr = qx + a * 512;
                    const ushort* qmr = qm + a * 512;
                    if constexpr (SC == 2) {
                        ushort2 x2 = *(const ushort2*)qxr;
                        s += __uint_as_float((unsigned)x2.x << 16)
                           + __uint_as_float((unsigned)x2.y << 16);
                        ushort2 m2_ = *(const ushort2*)qmr;
                        cnt += ((m2_.x >> cls) & 1) + ((m2_.y >> cls) & 1);
                    } else {
#pragma unroll
                        for (int e = 0; e < SC / 4; ++e) {
                            ushort4 x4 = *(const ushort4*)(qxr + 4 * e);
                            s += (__uint_as_float((unsigned)x4.x << 16)
                                + __uint_as_float((unsigned)x4.y << 16))
                               + (__uint_as_float((unsigned)x4.z << 16)
                                + __uint_as_float((unsigned)x4.w << 16));
                            ushort4 m4 = *(const ushort4*)(qmr + 4 * e);
                            cnt += (((m4.x >> cls) & 1) + ((m4.y >> cls) & 1))
                                 + (((m4.z >> cls) & 1) + ((m4.w >> cls) & 1));
                        }
                    }
                }
                xv = s * (1.f / (float)(SC * SC));
                yv = (ushort)(cnt << (8 - 2 * PIN));
            }
            if (inr) { sx[r * SS + c] = xv; syu[r * SS + c] = yv; }
            c += 4; r += 6;
            if (c >= 42) { c -= 42; r += 1; }
        }
    }
    __syncthreads();

    // ---- horizontal conv (5 moments)
    if (tid < 252) {
        int rr = tid / 6, s = tid - (tid / 6) * 6;
        int c0 = s * 6;
        const float* px = sx + rr * SS + c0;
        const ushort* pyu = syu + rr * SS + c0;
        float ac0[6] = {}, ac1[6] = {}, ac2[6] = {}, ac3[6] = {}, ac4[6] = {};
#pragma unroll
        for (int j = 0; j < 16; ++j) {
            float xv = px[j];
            float xx = xv * xv;
            float yv = (float)pyu[j];
            float xy = xv * yv;
            float yy = yv * yv;
#pragma unroll
            for (int o = 0; o < 6; ++o) {
                int kk = j - o;
                if (kk >= 0 && kk <= 10) {
                    float g = gk[kk];
                    ac0[o] = fmaf(g, xv, ac0[o]);
                    ac1[o] = fmaf(g, yv, ac1[o]);
                    ac2[o] = fmaf(g, xx, ac2[o]);
                    ac3[o] = fmaf(g, xy, ac3[o]);
                    ac4[o] = fmaf(g, yy, ac4[o]);
                }
            }
        }
        int ob = rr * TS + c0;
#pragma unroll
        for (int o = 0; o < 6; ++o) {
            if (c0 + o < 32) {
                // bf16 round-to-nearest (half-up) pack; all moments >= 0.
                unsigned ua = __float_as_uint(ac0[o]) + 0x8000u;
                unsigned ub = __float_as_uint(ac1[o]) + 0x8000u;
                unsigned uc = __float_as_uint(ac2[o]) + 0x8000u;
                unsigned ud = __float_as_uint(ac3[o]) + 0x8000u;
                unsigned ue = __float_as_uint(ac4[o]) + 0x8000u;
                tm4[ob + o] = make_uint2((ua >> 16) | (ub & 0xFFFF0000u),
                                         (uc >> 16) | (ud & 0xFFFF0000u));
                tm5[ob + o] = (ushort)(ue >> 16);
            }
        }
    }
    __syncthreads();

    // ---- vertical conv + SSIM (unpack bf16)
    const float C1 = 1e-4f, C2 = 9e-4f;
    const int cc = tid & 31, rg = tid >> 5, r0 = rg << 2;
    float a0[4] = {}, a1[4] = {}, a2[4] = {}, a3[4] = {}, a4[4] = {};
    const int vb = r0 * TS + cc;
#pragma unroll
    for (int k = 0; k < 14; ++k) {
        uint2 tv = tm4[vb + k * TS];
        float t0 = __uint_as_float(tv.x << 16);
        float t1 = __uint_as_float(tv.x & 0xFFFF0000u);
        float t2 = __uint_as_float(tv.y << 16);
        float t3 = __uint_as_float(tv.y & 0xFFFF0000u);
        float t4 = __uint_as_float((unsigned)tm5[vb + k * TS] << 16);
#pragma unroll
        for (int j = 0; j < 4; ++j) {
            int kk = k - j;
            if (kk >= 0 && kk <= 10) {
                float g = gk[kk];
                a0[j] = fmaf(g, t0, a0[j]);
                a1[j] = fmaf(g, t1, a1[j]);
                a2[j] = fmaf(g, t2, a2[j]);
                a3[j] = fmaf(g, t3, a3[j]);
                a4[j] = fmaf(g, t4, a4[j]);
            }
        }
    }
    float cs_l = 0.f, ss_l = 0.f;
    const bool colok = (ox + cc < OH);
#pragma unroll
    for (int j = 0; j < 4; ++j) {
        if (colok && (oy + r0 + j < OH)) {
            float m1 = a0[j];
            float m2 = a1[j] * (1.f / 256.f);
            float sxx = a2[j];
            float sxy_ = a3[j] * (1.f / 256.f);
            float syy_ = a4[j] * (1.f / 65536.f);
            float m11 = m1 * m1, m22 = m2 * m2, m12 = m1 * m2;
            float v1 = sxx - m11, v2 = syy_ - m22, cov = sxy_ - m12;
            float d1 = m11 + m22 + C1, d2 = v1 + v2 + C2;
            float n2 = 2.f * cov + C2;
            float q = 1.f / (d1 * d2);
            cs_l = fmaf(n2 * d1, q, cs_l);
            ss_l = fmaf((2.f * m12 + C1) * n2, q, ss_l);
        }
    }

    // ---- block reduction
    for (int offs = 32; offs; offs >>= 1) {
        cs_l += __shfl_down(cs_l, offs);
        ss_l += __shfl_down(ss_l, offs);
    }
    int wv = tid >> 6, ln = tid & 63;
    if (ln == 0) { red[wv] = cs_l; red[4 + wv] = ss_l; }
    __syncthreads();
    if (tid == 0) {
        double cs_b = (double)red[0] + (double)red[1] + (double)red[2] + (double)red[3];
        double ss_b = (double)red[4] + (double)red[5] + (double)red[6] + (double)red[7];
        atomicAdd(&acc[PIN * 96 + bc], cs_b);
        atomicAdd(&acc[PIN * 96 + 48 + bc], ss_b);
    }
}

// ---------------------------------------------------------------------------
// Scales 1-4 in ONE dispatch (4080 blocks), all sourcing X0/Y0m via inline
// pooling -> no inter-block dependency. Heaviest blocks first.
__global__ __launch_bounds__(256, 6)
void k_rest(const ushort* __restrict__ X0, const ushort* __restrict__ Y0m,
            double* __restrict__ acc) {
    __shared__ float sx[42 * 43 + 4];
    __shared__ uint2 tm4[42 * 35];           // bf16 packed: m1|m2, xx|xy
    __shared__ ushort tm5[42 * 35];          // bf16 yy
    __shared__ ushort syu[42 * 43 + 4];
    __shared__ float red[8];
    const int gb = blockIdx.x;

    if (gb < 48) {                          // scale 4: 1 tile x 48 bc
        ssim_tile_b<4>(X0, Y0m, 0, gb, acc, sx, tm4, tm5, syu, red);
    } else if (gb < 240) {                  // scale 3: 4 tiles x 48 bc
        int t = gb - 48;
        ssim_tile_b<3>(X0, Y0m, t & 3, t >> 2, acc, sx, tm4, tm5, syu, red);
    } else if (gb < 1008) {                 // scale 2: 16 tiles x 48 bc
        int t = gb - 240;
        ssim_tile_b<2>(X0, Y0m, t & 15, t >> 4, acc, sx, tm4, tm5, syu, red);
    } else {                                // scale 1: 64 tiles x 48 bc
        int t = gb - 1008;
        ssim_tile_b<1>(X0, Y0m, t & 63, t >> 6, acc, sx, tm4, tm5, syu, red);
    }
}

// ---------------------------------------------------------------------------
__global__ void k_final(const double* __restrict__ acc, float* __restrict__ out) {
    const float wts[5] = {0.0448f, 0.2856f, 0.3001f, 0.2363f, 0.1333f};
    const float cnt[5] = {252004.f, 60516.f, 13924.f, 2916.f, 484.f}; // 502^2..22^2
    int tid = threadIdx.x;
    float msss = 0.f;
    if (tid < BC) {
        msss = 1.f;
#pragma unroll
        for (int s = 0; s < 5; ++s) {
            double a = (s < 4) ? acc[s * 96 + tid] : acc[s * 96 + 48 + tid];
            float v = fmaxf((float)(a / (double)cnt[s]), 0.f);
            msss *= powf(v, wts[s]);
        }
    }
    for (int off = 32; off; off >>= 1) msss += __shfl_down(msss, off);
    if (tid == 0) out[0] = 1.f - msss * (1.f / (float)BC);
}

// ---------------------------------------------------------------------------
extern "C" void kernel_launch(void* const* d_in, const int* in_sizes, int n_in,
                              void* d_out, int out_size, void* d_ws, size_t ws_size,
                              hipStream_t stream) {
    const float* pred = (const float*)d_in[0];
    const int*   tgt  = (const int*)d_in[1];
    float* out = (float*)d_out;

    // workspace layout — 26.0 MB total (below the 27.9 MB proven in round 2)
    double* acc = (double*)d_ws;                        // 480 doubles (3840 B)
    ushort* X0  = (ushort*)(acc + 480);                 // [4,12,512,512] bf16 (24 MB)
    ushort* Y0m = X0 + (size_t)BC * HW0;                // [4,512,512] class mask (2 MB)

    k_prep<<<(NB * (HW0 / 4) + 255) / 256, 256, 0, stream>>>(
        (const float4*)pred, (const int4*)tgt, (ushort4*)X0, (ushort4*)Y0m, acc);

    k_ssim0<<<dim3(256, BC), 256, 0, stream>>>(X0, Y0m, acc);

    k_rest<<<dim3(4080), 256, 0, stream>>>(X0, Y0m, acc);

    k_final<<<1, 64, 0, stream>>>(acc, out);
}

// Round 5
// 235.442 us; speedup vs baseline: 1.4474x; 1.4474x over previous
//
#include <hip/hip_runtime.h>

#define NCH 12
#define NB  4
#define BC  48
#define HW0 (512 * 512)

// Gaussian 1-D weights (win=11, sigma=1.5), exact to f32 — computed offline.
#define GK_INIT { 0.00102840f, 0.00759863f, 0.03600078f, 0.10936081f, \
                  0.21300541f, 0.26601164f, 0.21300541f, 0.10936081f, \
                  0.03600078f, 0.00759863f, 0.00102840f }

// ---------------------------------------------------------------------------
// Prep: one thread per 2x2 patch. Computes softmax denominators (no
// max-subtraction: |pred|<=~6 -> no overflow), writes per-pixel U = 1/sum,
// AND the scale-1 pooled pyramid X1 (f32 avg of 2x2 softmax) + Y1 (one-hot
// count << 6) for all 12 classes — exactly the values k_ssim0's epilogue
// used to produce. This breaks the ssim0 -> rest dependency so both can
// run in ONE merged dispatch. Block 0 zero-inits the accumulators.
__global__ __launch_bounds__(256)
void k_prep(const float* __restrict__ pred, const int* __restrict__ tgt,
            float* __restrict__ U, float* __restrict__ X1,
            unsigned short* __restrict__ Y1, double* __restrict__ acc) {
    if (blockIdx.x == 0) {
        for (int t = threadIdx.x; t < 480; t += 256) acc[t] = 0.0;
    }
    const int blk = blockIdx.x;          // 0..1023
    const int b  = blk >> 8;             // batch
    const int py = blk & 255;            // patch row
    const int px = threadIdx.x;          // patch col
    const size_t o00 = (size_t)(2 * py) * 512 + 2 * px;
    const size_t o10 = o00 + 512;
    const float* Pb = pred + (size_t)b * NCH * HW0;

    // pass 1: denominators for the 4 pixels
    float s00 = 0.f, s01 = 0.f, s10 = 0.f, s11 = 0.f;
#pragma unroll
    for (int c = 0; c < NCH; ++c) {
        const float* pc = Pb + (size_t)c * HW0;
        float2 r0 = *(const float2*)(pc + o00);
        float2 r1 = *(const float2*)(pc + o10);
        s00 += __expf(r0.x); s01 += __expf(r0.y);
        s10 += __expf(r1.x); s11 += __expf(r1.y);
    }
    float u00 = 1.f / s00, u01 = 1.f / s01, u10 = 1.f / s10, u11 = 1.f / s11;
    float* Ub = U + (size_t)b * HW0;
    *(float2*)(Ub + o00) = make_float2(u00, u01);
    *(float2*)(Ub + o10) = make_float2(u10, u11);

    const int* Tb = tgt + (size_t)b * HW0;
    int2 t0 = *(const int2*)(Tb + o00);
    int2 t1 = *(const int2*)(Tb + o10);

    // pass 2: per-channel pooled outputs (pred re-reads are L1/L2-warm)
#pragma unroll
    for (int c = 0; c < NCH; ++c) {
        const float* pc = Pb + (size_t)c * HW0;
        float2 r0 = *(const float2*)(pc + o00);
        float2 r1 = *(const float2*)(pc + o10);
        float xs = __expf(r0.x) * u00 + __expf(r0.y) * u01
                 + __expf(r1.x) * u10 + __expf(r1.y) * u11;
        size_t oidx = ((size_t)(b * NCH + c) * 256 + py) * 256 + px;
        X1[oidx] = 0.25f * xs;
        unsigned cnt = (unsigned)(t0.x == c) + (unsigned)(t0.y == c)
                     + (unsigned)(t1.x == c) + (unsigned)(t1.y == c);
        Y1[oidx] = (unsigned short)(cnt << 6);
    }
}

// ---------------------------------------------------------------------------
// Shared-memory union for the merged kernel: scale-0 branch needs 19.3 KB,
// scales-1-4 branch needs 25.6 KB -> union 25.6 KB -> 6 blocks/CU.
union SMem {
    struct {
        float sx[42 * 43 + 4];
        uint2 tm4[42 * 35];
        unsigned long long ybits[30];
        float red[8];
    } s0;
    struct {
        float sx[42 * 43 + 4];
        uint2 tm4[42 * 35];
        unsigned short tm5[42 * 35];
        unsigned short syu[42 * 43 + 4];
        float red[8];
    } rg;
};

// ---------------------------------------------------------------------------
// Scale-0 SSIM tile (validated 250.8 µs body, epilogue REMOVED — X1/Y1 now
// come from k_prep). x = expf(pred)*u on the fly; y = one-hot ballot bits;
// bf16 truncated moment pack in LDS.
__device__ __forceinline__ void ssim0_tile(
    const float* __restrict__ pred, const float* __restrict__ U,
    const int* __restrict__ tgt, double* __restrict__ acc,
    int tile, int bc,
    float* sx, uint2* tm4, unsigned long long* ybits, float* red) {
    constexpr int SS = 43;
    constexpr int TS = 35;
    constexpr int H = 512, W = 512, OH = 502, OW = 502, tilesX = 16;
    const float gk[11] = GK_INIT;

    const int ty = tile / tilesX, tx = tile - ty * tilesX;
    const int oy = ty * 32, ox = tx * 32;
    const int tid = threadIdx.x;
    const bool interior = (oy + 41 < H) && (ox + 41 < W);

    const int b = bc / NCH, cls = bc - (bc / NCH) * NCH;
    const float* Pb = pred + (((size_t)b * NCH + cls) << 18);
    const float* Ub = U + ((size_t)b << 18);
    const int* Tb = tgt + ((size_t)b << 18);

    // ---- halo load 42x42: fused softmax x = expf(p)*u; y bits via ballot
    {
        int r = tid / 42, c = tid - (tid / 42) * 42;
#pragma unroll
        for (int k = 0; k < 7; ++k) {
            bool inr = (k < 6) || (tid < 228);
            int gy = oy + r, gx = ox + c;
            bool ld = inr && (interior || (gy < H && gx < W));
            float xv = 0.f;
            bool bit = false;
            if (ld) {
                int off = gy * W + gx;
                xv = expf(Pb[off]) * Ub[off];
                bit = (Tb[off] == cls);
            }
            unsigned long long mk = __ballot(bit);
            if ((tid & 63) == 0) ybits[(tid >> 6) + (k << 2)] = mk;
            if (inr) sx[r * SS + c] = xv;
            c += 4; r += 6;
            if (c >= 42) { c -= 42; r += 1; }
        }
        if (tid == 0) { ybits[28] = 0ull; ybits[29] = 0ull; }
    }
    __syncthreads();

    // ---- horizontal conv: 42 rows x 6 strips of 6 outputs (252 threads)
    if (tid < 252) {
        int rr = tid / 6, s = tid - (tid / 6) * 6;
        int c0 = s * 6;
        const float* px = sx + rr * SS + c0;
        float ac0[6] = {}, ac1[6] = {}, ac2[6] = {}, ac3[6] = {};
        unsigned long long win;
        {
            int i0 = rr * 42 + c0;
            int w = i0 >> 6, sh = i0 & 63;
            unsigned long long lo = ybits[w], hi = ybits[w + 1];
            win = sh ? ((lo >> sh) | (hi << (64 - sh))) : lo;
        }
#pragma unroll
        for (int j = 0; j < 16; ++j) {
            float xv = px[j];
            float xx = xv * xv;
            bool bit = (win >> j) & 1;
            float yv = bit ? 1.f : 0.f;
            float xy = bit ? xv : 0.f;
#pragma unroll
            for (int o = 0; o < 6; ++o) {
                int kk = j - o;
                if (kk >= 0 && kk <= 10) {
                    float g = gk[kk];
                    ac0[o] = fmaf(g, xv, ac0[o]);
                    ac1[o] = fmaf(g, yv, ac1[o]);
                    ac2[o] = fmaf(g, xx, ac2[o]);
                    ac3[o] = fmaf(g, xy, ac3[o]);
                }
            }
        }
        int ob = rr * TS + c0;
#pragma unroll
        for (int o = 0; o < 6; ++o) {
            if (c0 + o < 32) {
                unsigned ua = __float_as_uint(ac0[o]);
                unsigned ub = __float_as_uint(ac1[o]);
                unsigned uc = __float_as_uint(ac2[o]);
                unsigned ud = __float_as_uint(ac3[o]);
                tm4[ob + o] = make_uint2((ua >> 16) | (ub & 0xFFFF0000u),
                                         (uc >> 16) | (ud & 0xFFFF0000u));
            }
        }
    }
    __syncthreads();

    // ---- vertical conv + SSIM (unpack bf16 pairs)
    const float C1 = 1e-4f, C2 = 9e-4f;
    const int cc = tid & 31, rg = tid >> 5, r0 = rg << 2;
    float a0[4] = {}, a1[4] = {}, a2[4] = {}, a3[4] = {};
    const int vb = r0 * TS + cc;
#pragma unroll
    for (int k = 0; k < 14; ++k) {
        uint2 tv = tm4[vb + k * TS];
        float m1v = __uint_as_float(tv.x << 16);
        float m2v = __uint_as_float(tv.x & 0xFFFF0000u);
        float xxv = __uint_as_float(tv.y << 16);
        float xyv = __uint_as_float(tv.y & 0xFFFF0000u);
#pragma unroll
        for (int j = 0; j < 4; ++j) {
            int kk = k - j;
            if (kk >= 0 && kk <= 10) {
                float g = gk[kk];
                a0[j] = fmaf(g, m1v, a0[j]);
                a1[j] = fmaf(g, m2v, a1[j]);
                a2[j] = fmaf(g, xxv, a2[j]);
                a3[j] = fmaf(g, xyv, a3[j]);
            }
        }
    }
    float cs_l = 0.f, ss_l = 0.f;
    const bool colok = (ox + cc < OW);
#pragma unroll
    for (int j = 0; j < 4; ++j) {
        if (colok && (oy + r0 + j < OH)) {
            float m1 = a0[j], m2 = a1[j];
            float sxx = a2[j], sxy_ = a3[j];
            float m11 = m1 * m1, m22 = m2 * m2, m12 = m1 * m2;
            float v1 = sxx - m11, v2 = m2 - m22, cov = sxy_ - m12;  // y^2=y
            float d1 = m11 + m22 + C1, d2 = v1 + v2 + C2;
            float n2 = 2.f * cov + C2;
            float q = 1.f / (d1 * d2);
            cs_l = fmaf(n2 * d1, q, cs_l);
            ss_l = fmaf((2.f * m12 + C1) * n2, q, ss_l);
        }
    }

    // ---- block reduction
    for (int off = 32; off; off >>= 1) {
        cs_l += __shfl_down(cs_l, off);
        ss_l += __shfl_down(ss_l, off);
    }
    int wv = tid >> 6, ln = tid & 63;
    if (ln == 0) { red[wv] = cs_l; red[4 + wv] = ss_l; }
    __syncthreads();
    if (tid == 0) {
        double cs_b = (double)red[0] + (double)red[1] + (double)red[2] + (double)red[3];
        double ss_b = (double)red[4] + (double)red[5] + (double)red[6] + (double)red[7];
        atomicAdd(&acc[bc], cs_b);
        atomicAdd(&acc[48 + bc], ss_b);
    }
}

// ---------------------------------------------------------------------------
// Scales 1-4 tile body (validated round-1 form): sources X1/Y1 with inline
// SCxSC pooling (PIN=0 native for scale 1), bf16 round-to-nearest moment
// pack, vectorized pooled loads.
template <int PIN>
__device__ __forceinline__ void ssim_tile_g(
    const float* __restrict__ Xs, const unsigned short* __restrict__ Ys,
    int H, int W, int OH, int OW, int tilesX, int tile, int bc,
    double* __restrict__ acc, int scale,
    float* sx, uint2* tm4, unsigned short* tm5, unsigned short* syu, float* red) {
    constexpr int SS = 43;
    constexpr int TS = 35;
    const float gk[11] = GK_INIT;

    const int ty = tile / tilesX, tx = tile - ty * tilesX;
    const int oy = ty * 32, ox = tx * 32;
    const int tid = threadIdx.x;
    const bool interior = (oy + 41 < H) && (ox + 41 < W);

    constexpr int SC = 1 << PIN;
    const int SW = W * SC;
    const float* Xb = Xs + (size_t)bc * H * W * SC * SC;
    const unsigned short* Yb = Ys + (size_t)bc * H * W * SC * SC;

    // ---- halo load 42x42 (with inline source pooling for PIN>0)
    {
        int r = tid / 42, c = tid - (tid / 42) * 42;
#pragma unroll
        for (int k = 0; k < 7; ++k) {
            bool inr = (k < 6) || (tid < 228);
            int gy = oy + r, gx = ox + c;
            bool ld = inr && (interior || (gy < H && gx < W));
            float xv = 0.f;
            unsigned short yv = 0;
            if (ld) {
                if constexpr (PIN == 0) {
                    int off = gy * SW + gx;
                    xv = Xb[off];
                    yv = Yb[off];
                } else {
                    const float* q = Xb + (SC * gy) * SW + SC * gx;
                    const unsigned short* qy = Yb + (SC * gy) * SW + SC * gx;
                    float s = 0.f; unsigned us = 0;
#pragma unroll
                    for (int a = 0; a < SC; ++a) {
                        const float* qr = q + a * SW;
                        const unsigned short* qyr = qy + a * SW;
                        if constexpr (PIN == 1) {
                            float2 f = *(const float2*)qr;
                            s += f.x + f.y;
                            ushort2 uy = *(const ushort2*)qyr;
                            us += (unsigned)uy.x + (unsigned)uy.y;
                        } else {
#pragma unroll
                            for (int e4 = 0; e4 < SC / 4; ++e4) {
                                float4 f = *(const float4*)(qr + e4 * 4);
                                s += (f.x + f.y) + (f.z + f.w);
                                ushort4 uy = *(const ushort4*)(qyr + e4 * 4);
                                us += ((unsigned)uy.x + (unsigned)uy.y)
                                    + ((unsigned)uy.z + (unsigned)uy.w);
                            }
                        }
                    }
                    xv = s * (1.f / (float)(SC * SC));
                    yv = (unsigned short)(us >> (2 * PIN));
                }
            }
            if (inr) { sx[r * SS + c] = xv; syu[r * SS + c] = yv; }
            c += 4; r += 6;
            if (c >= 42) { c -= 42; r += 1; }
        }
    }
    __syncthreads();

    // ---- horizontal conv (5 moments)
    if (tid < 252) {
        int rr = tid / 6, s = tid - (tid / 6) * 6;
        int c0 = s * 6;
        const float* px = sx + rr * SS + c0;
        const unsigned short* pyu = syu + rr * SS + c0;
        float ac0[6] = {}, ac1[6] = {}, ac2[6] = {}, ac3[6] = {}, ac4[6] = {};
#pragma unroll
        for (int j = 0; j < 16; ++j) {
            float xv = px[j];
            float xx = xv * xv;
            float yv = (float)pyu[j];
            float xy = xv * yv;
            float yy = yv * yv;
#pragma unroll
            for (int o = 0; o < 6; ++o) {
                int kk = j - o;
                if (kk >= 0 && kk <= 10) {
                    float g = gk[kk];
                    ac0[o] = fmaf(g, xv, ac0[o]);
                    ac1[o] = fmaf(g, yv, ac1[o]);
                    ac2[o] = fmaf(g, xx, ac2[o]);
                    ac3[o] = fmaf(g, xy, ac3[o]);
                    ac4[o] = fmaf(g, yy, ac4[o]);
                }
            }
        }
        int ob = rr * TS + c0;
#pragma unroll
        for (int o = 0; o < 6; ++o) {
            if (c0 + o < 32) {
                // bf16 round-to-nearest (half-up) pack; all moments >= 0.
                unsigned ua = __float_as_uint(ac0[o]) + 0x8000u;
                unsigned ub = __float_as_uint(ac1[o]) + 0x8000u;
                unsigned uc = __float_as_uint(ac2[o]) + 0x8000u;
                unsigned ud = __float_as_uint(ac3[o]) + 0x8000u;
                unsigned ue = __float_as_uint(ac4[o]) + 0x8000u;
                tm4[ob + o] = make_uint2((ua >> 16) | (ub & 0xFFFF0000u),
                                         (uc >> 16) | (ud & 0xFFFF0000u));
                tm5[ob + o] = (unsigned short)(ue >> 16);
            }
        }
    }
    __syncthreads();

    // ---- vertical conv + SSIM (unpack bf16)
    const float C1 = 1e-4f, C2 = 9e-4f;
    const int cc = tid & 31, rg = tid >> 5, r0 = rg << 2;
    float a0[4] = {}, a1[4] = {}, a2[4] = {}, a3[4] = {}, a4[4] = {};
    const int vb = r0 * TS + cc;
#pragma unroll
    for (int k = 0; k < 14; ++k) {
        uint2 tv = tm4[vb + k * TS];
        float t0 = __uint_as_float(tv.x << 16);
        float t1 = __uint_as_float(tv.x & 0xFFFF0000u);
        float t2 = __uint_as_float(tv.y << 16);
        float t3 = __uint_as_float(tv.y & 0xFFFF0000u);
        float t4 = __uint_as_float((unsigned)tm5[vb + k * TS] << 16);
#pragma unroll
        for (int j = 0; j < 4; ++j) {
            int kk = k - j;
            if (kk >= 0 && kk <= 10) {
                float g = gk[kk];
                a0[j] = fmaf(g, t0, a0[j]);
                a1[j] = fmaf(g, t1, a1[j]);
                a2[j] = fmaf(g, t2, a2[j]);
                a3[j] = fmaf(g, t3, a3[j]);
                a4[j] = fmaf(g, t4, a4[j]);
            }
        }
    }
    float cs_l = 0.f, ss_l = 0.f;
    const bool colok = (ox + cc < OW);
#pragma unroll
    for (int j = 0; j < 4; ++j) {
        if (colok && (oy + r0 + j < OH)) {
            float m1 = a0[j];
            float m2 = a1[j] * (1.f / 256.f);
            float sxx = a2[j];
            float sxy_ = a3[j] * (1.f / 256.f);
            float syy_ = a4[j] * (1.f / 65536.f);
            float m11 = m1 * m1, m22 = m2 * m2, m12 = m1 * m2;
            float v1 = sxx - m11, v2 = syy_ - m22, cov = sxy_ - m12;
            float d1 = m11 + m22 + C1, d2 = v1 + v2 + C2;
            float n2 = 2.f * cov + C2;
            float q = 1.f / (d1 * d2);
            cs_l = fmaf(n2 * d1, q, cs_l);
            ss_l = fmaf((2.f * m12 + C1) * n2, q, ss_l);
        }
    }

    // ---- block reduction
    for (int offs = 32; offs; offs >>= 1) {
        cs_l += __shfl_down(cs_l, offs);
        ss_l += __shfl_down(ss_l, offs);
    }
    int wv = tid >> 6, ln = tid & 63;
    if (ln == 0) { red[wv] = cs_l; red[4 + wv] = ss_l; }
    __syncthreads();
    if (tid == 0) {
        double cs_b = (double)red[0] + (double)red[1] + (double)red[2] + (double)red[3];
        double ss_b = (double)red[4] + (double)red[5] + (double)red[6] + (double)red[7];
        atomicAdd(&acc[scale * 96 + bc], cs_b);
        atomicAdd(&acc[scale * 96 + 48 + bc], ss_b);
    }
}

// ---------------------------------------------------------------------------
// MERGED dispatch: 16368 blocks = 12288 scale-0 + 4080 scales-1-4.
// Interleaved so each CU co-schedules VALU-heavy scale-0 blocks with
// latency-bound rest blocks: for gb < 16320, every 4th block (gb%4==0) is a
// rest block; the 48 tail blocks are scale-0. Rest sub-order: heavy
// (scale 4) first.
__global__ __launch_bounds__(256, 6)
void k_main(const float* __restrict__ pred, const float* __restrict__ U,
            const int* __restrict__ tgt,
            const float* __restrict__ X1, const unsigned short* __restrict__ Y1,
            double* __restrict__ acc) {
    __shared__ SMem sm;
    const int gb = blockIdx.x;

    int s0_idx = -1, rest_idx = -1;
    if (gb < 16320) {
        int r = gb & 3, q = gb >> 2;
        if (r == 0) rest_idx = q;                 // 4080 rest blocks
        else        s0_idx = 3 * q + (r - 1);     // 12240 scale-0 blocks
    } else {
        s0_idx = 12240 + (gb - 16320);            // last 48 scale-0 blocks
    }

    if (s0_idx >= 0) {
        ssim0_tile(pred, U, tgt, acc, s0_idx & 255, s0_idx >> 8,
                   sm.s0.sx, sm.s0.tm4, sm.s0.ybits, sm.s0.red);
        return;
    }
    const int gq = rest_idx;
    if (gq < 48) {                          // scale 4: 1 tile x 48 bc
        ssim_tile_g<3>(X1, Y1, 32, 32, 22, 22, 1, 0, gq,
                       acc, 4, sm.rg.sx, sm.rg.tm4, sm.rg.tm5, sm.rg.syu, sm.rg.red);
    } else if (gq < 240) {                  // scale 3: 4 tiles x 48 bc
        int t = gq - 48;
        ssim_tile_g<2>(X1, Y1, 64, 64, 54, 54, 2, t & 3, t >> 2,
                       acc, 3, sm.rg.sx, sm.rg.tm4, sm.rg.tm5, sm.rg.syu, sm.rg.red);
    } else if (gq < 1008) {                 // scale 2: 16 tiles x 48 bc
        int t = gq - 240;
        ssim_tile_g<1>(X1, Y1, 128, 128, 118, 118, 4, t & 15, t >> 4,
                       acc, 2, sm.rg.sx, sm.rg.tm4, sm.rg.tm5, sm.rg.syu, sm.rg.red);
    } else {                                // scale 1: 64 tiles x 48 bc
        int t = gq - 1008;
        ssim_tile_g<0>(X1, Y1, 256, 256, 246, 246, 8, t & 63, t >> 6,
                       acc, 1, sm.rg.sx, sm.rg.tm4, sm.rg.tm5, sm.rg.syu, sm.rg.red);
    }
}

// ---------------------------------------------------------------------------
__global__ void k_final(const double* __restrict__ acc, float* __restrict__ out) {
    const float wts[5] = {0.0448f, 0.2856f, 0.3001f, 0.2363f, 0.1333f};
    const float cnt[5] = {252004.f, 60516.f, 13924.f, 2916.f, 484.f}; // 502^2..22^2
    int tid = threadIdx.x;
    float msss = 0.f;
    if (tid < BC) {
        msss = 1.f;
#pragma unroll
        for (int s = 0; s < 5; ++s) {
            double a = (s < 4) ? acc[s * 96 + tid] : acc[s * 96 + 48 + tid];
            float v = fmaxf((float)(a / (double)cnt[s]), 0.f);
            msss *= powf(v, wts[s]);
        }
    }
    for (int off = 32; off; off >>= 1) msss += __shfl_down(msss, off);
    if (tid == 0) out[0] = 1.f - msss * (1.f / (float)BC);
}

// ---------------------------------------------------------------------------
extern "C" void kernel_launch(void* const* d_in, const int* in_sizes, int n_in,
                              void* d_out, int out_size, void* d_ws, size_t ws_size,
                              hipStream_t stream) {
    const float* pred = (const float*)d_in[0];
    const int*   tgt  = (const int*)d_in[1];
    float* out = (float*)d_out;

    // workspace layout — 22.1 MB (26 MB proven safe in round 4)
    double* acc = (double*)d_ws;                       // 480 doubles
    float* U  = (float*)(acc + 480);                   // [4,512,512]      4 MB
    float* X1 = U + (size_t)NB * HW0;                  // [48,256,256]    12 MB
    unsigned short* Y1 = (unsigned short*)(X1 + (size_t)BC * 65536);  // 6 MB

    k_prep<<<1024, 256, 0, stream>>>(pred, tgt, U, X1, Y1, acc);

    k_main<<<16368, 256, 0, stream>>>(pred, U, tgt, X1, Y1, acc);

    k_final<<<1, 64, 0, stream>>>(acc, out);
}

// Round 6
// 222.262 us; speedup vs baseline: 1.5332x; 1.0593x over previous
//
#include <hip/hip_runtime.h>

#define NCH 12
#define NB  4
#define BC  48
#define HW0 (512 * 512)

// Gaussian 1-D weights (win=11, sigma=1.5), exact to f32 — computed offline.
#define GK_INIT { 0.00102840f, 0.00759863f, 0.03600078f, 0.10936081f, \
                  0.21300541f, 0.26601164f, 0.21300541f, 0.10936081f, \
                  0.03600078f, 0.00759863f, 0.00102840f }

// ---------------------------------------------------------------------------
// Prep (SINGLE-PASS): one thread per 2x2 patch; exp values for all 12
// channels x 4 pixels held in registers (48 VGPR) -> no second read/exp pass.
// Writes per-pixel U = 1/sum, X1 (2x2-pooled softmax, f32) and Y1 (one-hot
// count << 6). Block 0 zero-inits the accumulators.
__global__ __launch_bounds__(256)
void k_prep(const float* __restrict__ pred, const int* __restrict__ tgt,
            float* __restrict__ U, float* __restrict__ X1,
            unsigned short* __restrict__ Y1, double* __restrict__ acc) {
    if (blockIdx.x == 0) {
        for (int t = threadIdx.x; t < 480; t += 256) acc[t] = 0.0;
    }
    const int blk = blockIdx.x;          // 0..1023
    const int b  = blk >> 8;             // batch
    const int py = blk & 255;            // patch row
    const int px = threadIdx.x;          // patch col
    const size_t o00 = (size_t)(2 * py) * 512 + 2 * px;
    const size_t o10 = o00 + 512;
    const float* Pb = pred + (size_t)b * NCH * HW0;

    float ex[NCH], ey[NCH], ez[NCH], ew[NCH];
    float s00 = 0.f, s01 = 0.f, s10 = 0.f, s11 = 0.f;
#pragma unroll
    for (int c = 0; c < NCH; ++c) {
        const float* pc = Pb + (size_t)c * HW0;
        float2 r0 = *(const float2*)(pc + o00);
        float2 r1 = *(const float2*)(pc + o10);
        ex[c] = __expf(r0.x); ey[c] = __expf(r0.y);
        ez[c] = __expf(r1.x); ew[c] = __expf(r1.y);
        s00 += ex[c]; s01 += ey[c]; s10 += ez[c]; s11 += ew[c];
    }
    float u00 = 1.f / s00, u01 = 1.f / s01, u10 = 1.f / s10, u11 = 1.f / s11;
    float* Ub = U + (size_t)b * HW0;
    *(float2*)(Ub + o00) = make_float2(u00, u01);
    *(float2*)(Ub + o10) = make_float2(u10, u11);

    const int* Tb = tgt + (size_t)b * HW0;
    int2 t0 = *(const int2*)(Tb + o00);
    int2 t1 = *(const int2*)(Tb + o10);

#pragma unroll
    for (int c = 0; c < NCH; ++c) {
        float xs = ex[c] * u00 + ey[c] * u01 + ez[c] * u10 + ew[c] * u11;
        size_t oidx = ((size_t)(b * NCH + c) * 256 + py) * 256 + px;
        X1[oidx] = 0.25f * xs;
        unsigned cnt = (unsigned)(t0.x == c) + (unsigned)(t0.y == c)
                     + (unsigned)(t1.x == c) + (unsigned)(t1.y == c);
        Y1[oidx] = (unsigned short)(cnt << 6);
    }
}

// ---------------------------------------------------------------------------
// Shared-memory union: scale-0 branch 19.3 KB; rest branch packed to
// 21.97 KB ({x bf16 | y u16} in one uint) -> 7 blocks/CU (was 6 at 25.6 KB).
union SMem {
    struct {
        float sx[42 * 43 + 4];
        uint2 tm4[42 * 35];
        unsigned long long ybits[30];
        float red[8];
    } s0;
    struct {
        unsigned int sxy[42 * 43 + 4];   // hi16: y count (0..256); lo16: x bf16
        uint2 tm4[42 * 35];
        unsigned short tm5[42 * 35];
        float red[8];
    } rg;
};

// ---------------------------------------------------------------------------
// Scale-0 SSIM tile (validated body; __expf in halo — merged kernel is
// VALU-bound so the ~8-op/pixel saving now converts to time).
__device__ __forceinline__ void ssim0_tile(
    const float* __restrict__ pred, const float* __restrict__ U,
    const int* __restrict__ tgt, double* __restrict__ acc,
    int tile, int bc,
    float* sx, uint2* tm4, unsigned long long* ybits, float* red) {
    constexpr int SS = 43;
    constexpr int TS = 35;
    constexpr int H = 512, W = 512, OH = 502, OW = 502, tilesX = 16;
    const float gk[11] = GK_INIT;

    const int ty = tile / tilesX, tx = tile - ty * tilesX;
    const int oy = ty * 32, ox = tx * 32;
    const int tid = threadIdx.x;
    const bool interior = (oy + 41 < H) && (ox + 41 < W);

    const int b = bc / NCH, cls = bc - (bc / NCH) * NCH;
    const float* Pb = pred + (((size_t)b * NCH + cls) << 18);
    const float* Ub = U + ((size_t)b << 18);
    const int* Tb = tgt + ((size_t)b << 18);

    // ---- halo load 42x42: fused softmax x = __expf(p)*u; y bits via ballot
    {
        int r = tid / 42, c = tid - (tid / 42) * 42;
#pragma unroll
        for (int k = 0; k < 7; ++k) {
            bool inr = (k < 6) || (tid < 228);
            int gy = oy + r, gx = ox + c;
            bool ld = inr && (interior || (gy < H && gx < W));
            float xv = 0.f;
            bool bit = false;
            if (ld) {
                int off = gy * W + gx;
                xv = __expf(Pb[off]) * Ub[off];
                bit = (Tb[off] == cls);
            }
            unsigned long long mk = __ballot(bit);
            if ((tid & 63) == 0) ybits[(tid >> 6) + (k << 2)] = mk;
            if (inr) sx[r * SS + c] = xv;
            c += 4; r += 6;
            if (c >= 42) { c -= 42; r += 1; }
        }
        if (tid == 0) { ybits[28] = 0ull; ybits[29] = 0ull; }
    }
    __syncthreads();

    // ---- horizontal conv: 42 rows x 6 strips of 6 outputs (252 threads)
    if (tid < 252) {
        int rr = tid / 6, s = tid - (tid / 6) * 6;
        int c0 = s * 6;
        const float* px = sx + rr * SS + c0;
        float ac0[6] = {}, ac1[6] = {}, ac2[6] = {}, ac3[6] = {};
        unsigned long long win;
        {
            int i0 = rr * 42 + c0;
            int w = i0 >> 6, sh = i0 & 63;
            unsigned long long lo = ybits[w], hi = ybits[w + 1];
            win = sh ? ((lo >> sh) | (hi << (64 - sh))) : lo;
        }
#pragma unroll
        for (int j = 0; j < 16; ++j) {
            float xv = px[j];
            float xx = xv * xv;
            bool bit = (win >> j) & 1;
            float yv = bit ? 1.f : 0.f;
            float xy = bit ? xv : 0.f;
#pragma unroll
            for (int o = 0; o < 6; ++o) {
                int kk = j - o;
                if (kk >= 0 && kk <= 10) {
                    float g = gk[kk];
                    ac0[o] = fmaf(g, xv, ac0[o]);
                    ac1[o] = fmaf(g, yv, ac1[o]);
                    ac2[o] = fmaf(g, xx, ac2[o]);
                    ac3[o] = fmaf(g, xy, ac3[o]);
                }
            }
        }
        int ob = rr * TS + c0;
#pragma unroll
        for (int o = 0; o < 6; ++o) {
            if (c0 + o < 32) {
                unsigned ua = __float_as_uint(ac0[o]);
                unsigned ub = __float_as_uint(ac1[o]);
                unsigned uc = __float_as_uint(ac2[o]);
                unsigned ud = __float_as_uint(ac3[o]);
                tm4[ob + o] = make_uint2((ua >> 16) | (ub & 0xFFFF0000u),
                                         (uc >> 16) | (ud & 0xFFFF0000u));
            }
        }
    }
    __syncthreads();

    // ---- vertical conv + SSIM (unpack bf16 pairs)
    const float C1 = 1e-4f, C2 = 9e-4f;
    const int cc = tid & 31, rg = tid >> 5, r0 = rg << 2;
    float a0[4] = {}, a1[4] = {}, a2[4] = {}, a3[4] = {};
    const int vb = r0 * TS + cc;
#pragma unroll
    for (int k = 0; k < 14; ++k) {
        uint2 tv = tm4[vb + k * TS];
        float m1v = __uint_as_float(tv.x << 16);
        float m2v = __uint_as_float(tv.x & 0xFFFF0000u);
        float xxv = __uint_as_float(tv.y << 16);
        float xyv = __uint_as_float(tv.y & 0xFFFF0000u);
#pragma unroll
        for (int j = 0; j < 4; ++j) {
            int kk = k - j;
            if (kk >= 0 && kk <= 10) {
                float g = gk[kk];
                a0[j] = fmaf(g, m1v, a0[j]);
                a1[j] = fmaf(g, m2v, a1[j]);
                a2[j] = fmaf(g, xxv, a2[j]);
                a3[j] = fmaf(g, xyv, a3[j]);
            }
        }
    }
    float cs_l = 0.f, ss_l = 0.f;
    const bool colok = (ox + cc < OW);
#pragma unroll
    for (int j = 0; j < 4; ++j) {
        if (colok && (oy + r0 + j < OH)) {
            float m1 = a0[j], m2 = a1[j];
            float sxx = a2[j], sxy_ = a3[j];
            float m11 = m1 * m1, m22 = m2 * m2, m12 = m1 * m2;
            float v1 = sxx - m11, v2 = m2 - m22, cov = sxy_ - m12;  // y^2=y
            float d1 = m11 + m22 + C1, d2 = v1 + v2 + C2;
            float n2 = 2.f * cov + C2;
            float q = 1.f / (d1 * d2);
            cs_l = fmaf(n2 * d1, q, cs_l);
            ss_l = fmaf((2.f * m12 + C1) * n2, q, ss_l);
        }
    }

    // ---- block reduction
    for (int off = 32; off; off >>= 1) {
        cs_l += __shfl_down(cs_l, off);
        ss_l += __shfl_down(ss_l, off);
    }
    int wv = tid >> 6, ln = tid & 63;
    if (ln == 0) { red[wv] = cs_l; red[4 + wv] = ss_l; }
    __syncthreads();
    if (tid == 0) {
        double cs_b = (double)red[0] + (double)red[1] + (double)red[2] + (double)red[3];
        double ss_b = (double)red[4] + (double)red[5] + (double)red[6] + (double)red[7];
        atomicAdd(&acc[bc], cs_b);
        atomicAdd(&acc[48 + bc], ss_b);
    }
}

// ---------------------------------------------------------------------------
// Scales 1-4 tile body. LDS input now one packed uint per pixel:
// hi16 = y count (0..256), lo16 = x bf16 (round-to-nearest). Saves 3.6 KB
// LDS -> 7 blocks/CU. Moments still bf16-packed (validated).
template <int PIN>
__device__ __forceinline__ void ssim_tile_g(
    const float* __restrict__ Xs, const unsigned short* __restrict__ Ys,
    int H, int W, int OH, int OW, int tilesX, int tile, int bc,
    double* __restrict__ acc, int scale,
    unsigned int* sxy, uint2* tm4, unsigned short* tm5, float* red) {
    constexpr int SS = 43;
    constexpr int TS = 35;
    const float gk[11] = GK_INIT;

    const int ty = tile / tilesX, tx = tile - ty * tilesX;
    const int oy = ty * 32, ox = tx * 32;
    const int tid = threadIdx.x;
    const bool interior = (oy + 41 < H) && (ox + 41 < W);

    constexpr int SC = 1 << PIN;
    const int SW = W * SC;
    const float* Xb = Xs + (size_t)bc * H * W * SC * SC;
    const unsigned short* Yb = Ys + (size_t)bc * H * W * SC * SC;

    // ---- halo load 42x42 (inline source pooling for PIN>0), packed store
    {
        int r = tid / 42, c = tid - (tid / 42) * 42;
#pragma unroll
        for (int k = 0; k < 7; ++k) {
            bool inr = (k < 6) || (tid < 228);
            int gy = oy + r, gx = ox + c;
            bool ld = inr && (interior || (gy < H && gx < W));
            float xv = 0.f;
            unsigned yc = 0;
            if (ld) {
                if constexpr (PIN == 0) {
                    int off = gy * SW + gx;
                    xv = Xb[off];
                    yc = Yb[off];
                } else {
                    const float* q = Xb + (SC * gy) * SW + SC * gx;
                    const unsigned short* qy = Yb + (SC * gy) * SW + SC * gx;
                    float s = 0.f; unsigned us = 0;
#pragma unroll
                    for (int a = 0; a < SC; ++a) {
                        const float* qr = q + a * SW;
                        const unsigned short* qyr = qy + a * SW;
                        if constexpr (PIN == 1) {
                            float2 f = *(const float2*)qr;
                            s += f.x + f.y;
                            ushort2 uy = *(const ushort2*)qyr;
                            us += (unsigned)uy.x + (unsigned)uy.y;
                        } else {
#pragma unroll
                            for (int e4 = 0; e4 < SC / 4; ++e4) {
                                float4 f = *(const float4*)(qr + e4 * 4);
                                s += (f.x + f.y) + (f.z + f.w);
                                ushort4 uy = *(const ushort4*)(qyr + e4 * 4);
                                us += ((unsigned)uy.x + (unsigned)uy.y)
                                    + ((unsigned)uy.z + (unsigned)uy.w);
                            }
                        }
                    }
                    xv = s * (1.f / (float)(SC * SC));
                    yc = us >> (2 * PIN);
                }
            }
            if (inr) {
                unsigned xb = (__float_as_uint(xv) + 0x8000u) >> 16;  // bf16 rn
                sxy[r * SS + c] = (yc << 16) | xb;
            }
            c += 4; r += 6;
            if (c >= 42) { c -= 42; r += 1; }
        }
    }
    __syncthreads();

    // ---- horizontal conv (5 moments) from packed input
    if (tid < 252) {
        int rr = tid / 6, s = tid - (tid / 6) * 6;
        int c0 = s * 6;
        const unsigned int* pxy = sxy + rr * SS + c0;
        float ac0[6] = {}, ac1[6] = {}, ac2[6] = {}, ac3[6] = {}, ac4[6] = {};
#pragma unroll
        for (int j = 0; j < 16; ++j) {
            unsigned v = pxy[j];
            float xv = __uint_as_float(v << 16);
            float yv = (float)(v >> 16);
            float xx = xv * xv;
            float xy = xv * yv;
            float yy = yv * yv;
#pragma unroll
            for (int o = 0; o < 6; ++o) {
                int kk = j - o;
                if (kk >= 0 && kk <= 10) {
                    float g = gk[kk];
                    ac0[o] = fmaf(g, xv, ac0[o]);
                    ac1[o] = fmaf(g, yv, ac1[o]);
                    ac2[o] = fmaf(g, xx, ac2[o]);
                    ac3[o] = fmaf(g, xy, ac3[o]);
                    ac4[o] = fmaf(g, yy, ac4[o]);
                }
            }
        }
        int ob = rr * TS + c0;
#pragma unroll
        for (int o = 0; o < 6; ++o) {
            if (c0 + o < 32) {
                // bf16 round-to-nearest (half-up) pack; all moments >= 0.
                unsigned ua = __float_as_uint(ac0[o]) + 0x8000u;
                unsigned ub = __float_as_uint(ac1[o]) + 0x8000u;
                unsigned uc = __float_as_uint(ac2[o]) + 0x8000u;
                unsigned ud = __float_as_uint(ac3[o]) + 0x8000u;
                unsigned ue = __float_as_uint(ac4[o]) + 0x8000u;
                tm4[ob + o] = make_uint2((ua >> 16) | (ub & 0xFFFF0000u),
                                         (uc >> 16) | (ud & 0xFFFF0000u));
                tm5[ob + o] = (unsigned short)(ue >> 16);
            }
        }
    }
    __syncthreads();

    // ---- vertical conv + SSIM (unpack bf16)
    const float C1 = 1e-4f, C2 = 9e-4f;
    const int cc = tid & 31, rg = tid >> 5, r0 = rg << 2;
    float a0[4] = {}, a1[4] = {}, a2[4] = {}, a3[4] = {}, a4[4] = {};
    const int vb = r0 * TS + cc;
#pragma unroll
    for (int k = 0; k < 14; ++k) {
        uint2 tv = tm4[vb + k * TS];
        float t0 = __uint_as_float(tv.x << 16);
        float t1 = __uint_as_float(tv.x & 0xFFFF0000u);
        float t2 = __uint_as_float(tv.y << 16);
        float t3 = __uint_as_float(tv.y & 0xFFFF0000u);
        float t4 = __uint_as_float((unsigned)tm5[vb + k * TS] << 16);
#pragma unroll
        for (int j = 0; j < 4; ++j) {
            int kk = k - j;
            if (kk >= 0 && kk <= 10) {
                float g = gk[kk];
                a0[j] = fmaf(g, t0, a0[j]);
                a1[j] = fmaf(g, t1, a1[j]);
                a2[j] = fmaf(g, t2, a2[j]);
                a3[j] = fmaf(g, t3, a3[j]);
                a4[j] = fmaf(g, t4, a4[j]);
            }
        }
    }
    float cs_l = 0.f, ss_l = 0.f;
    const bool colok = (ox + cc < OW);
#pragma unroll
    for (int j = 0; j < 4; ++j) {
        if (colok && (oy + r0 + j < OH)) {
            float m1 = a0[j];
            float m2 = a1[j] * (1.f / 256.f);
            float sxx = a2[j];
            float sxy_ = a3[j] * (1.f / 256.f);
            float syy_ = a4[j] * (1.f / 65536.f);
            float m11 = m1 * m1, m22 = m2 * m2, m12 = m1 * m2;
            float v1 = sxx - m11, v2 = syy_ - m22, cov = sxy_ - m12;
            float d1 = m11 + m22 + C1, d2 = v1 + v2 + C2;
            float n2 = 2.f * cov + C2;
            float q = 1.f / (d1 * d2);
            cs_l = fmaf(n2 * d1, q, cs_l);
            ss_l = fmaf((2.f * m12 + C1) * n2, q, ss_l);
        }
    }

    // ---- block reduction
    for (int offs = 32; offs; offs >>= 1) {
        cs_l += __shfl_down(cs_l, offs);
        ss_l += __shfl_down(ss_l, offs);
    }
    int wv = tid >> 6, ln = tid & 63;
    if (ln == 0) { red[wv] = cs_l; red[4 + wv] = ss_l; }
    __syncthreads();
    if (tid == 0) {
        double cs_b = (double)red[0] + (double)red[1] + (double)red[2] + (double)red[3];
        double ss_b = (double)red[4] + (double)red[5] + (double)red[6] + (double)red[7];
        atomicAdd(&acc[scale * 96 + bc], cs_b);
        atomicAdd(&acc[scale * 96 + 48 + bc], ss_b);
    }
}

// ---------------------------------------------------------------------------
// MERGED dispatch: 16368 blocks = 12288 scale-0 + 4080 scales-1-4,
// interleaved (every 4th block a rest block; rest sub-order heavy-first).
__global__ __launch_bounds__(256, 7)
void k_main(const float* __restrict__ pred, const float* __restrict__ U,
            const int* __restrict__ tgt,
            const float* __restrict__ X1, const unsigned short* __restrict__ Y1,
            double* __restrict__ acc) {
    __shared__ SMem sm;
    const int gb = blockIdx.x;

    int s0_idx = -1, rest_idx = -1;
    if (gb < 16320) {
        int r = gb & 3, q = gb >> 2;
        if (r == 0) rest_idx = q;                 // 4080 rest blocks
        else        s0_idx = 3 * q + (r - 1);     // 12240 scale-0 blocks
    } else {
        s0_idx = 12240 + (gb - 16320);            // last 48 scale-0 blocks
    }

    if (s0_idx >= 0) {
        ssim0_tile(pred, U, tgt, acc, s0_idx & 255, s0_idx >> 8,
                   sm.s0.sx, sm.s0.tm4, sm.s0.ybits, sm.s0.red);
        return;
    }
    const int gq = rest_idx;
    if (gq < 48) {                          // scale 4: 1 tile x 48 bc
        ssim_tile_g<3>(X1, Y1, 32, 32, 22, 22, 1, 0, gq,
                       acc, 4, sm.rg.sxy, sm.rg.tm4, sm.rg.tm5, sm.rg.red);
    } else if (gq < 240) {                  // scale 3: 4 tiles x 48 bc
        int t = gq - 48;
        ssim_tile_g<2>(X1, Y1, 64, 64, 54, 54, 2, t & 3, t >> 2,
                       acc, 3, sm.rg.sxy, sm.rg.tm4, sm.rg.tm5, sm.rg.red);
    } else if (gq < 1008) {                 // scale 2: 16 tiles x 48 bc
        int t = gq - 240;
        ssim_tile_g<1>(X1, Y1, 128, 128, 118, 118, 4, t & 15, t >> 4,
                       acc, 2, sm.rg.sxy, sm.rg.tm4, sm.rg.tm5, sm.rg.red);
    } else {                                // scale 1: 64 tiles x 48 bc
        int t = gq - 1008;
        ssim_tile_g<0>(X1, Y1, 256, 256, 246, 246, 8, t & 63, t >> 6,
                       acc, 1, sm.rg.sxy, sm.rg.tm4, sm.rg.tm5, sm.rg.red);
    }
}

// ---------------------------------------------------------------------------
__global__ void k_final(const double* __restrict__ acc, float* __restrict__ out) {
    const float wts[5] = {0.0448f, 0.2856f, 0.3001f, 0.2363f, 0.1333f};
    const float cnt[5] = {252004.f, 60516.f, 13924.f, 2916.f, 484.f}; // 502^2..22^2
    int tid = threadIdx.x;
    float msss = 0.f;
    if (tid < BC) {
        msss = 1.f;
#pragma unroll
        for (int s = 0; s < 5; ++s) {
            double a = (s < 4) ? acc[s * 96 + tid] : acc[s * 96 + 48 + tid];
            float v = fmaxf((float)(a / (double)cnt[s]), 0.f);
            msss *= powf(v, wts[s]);
        }
    }
    for (int off = 32; off; off >>= 1) msss += __shfl_down(msss, off);
    if (tid == 0) out[0] = 1.f - msss * (1.f / (float)BC);
}

// ---------------------------------------------------------------------------
extern "C" void kernel_launch(void* const* d_in, const int* in_sizes, int n_in,
                              void* d_out, int out_size, void* d_ws, size_t ws_size,
                              hipStream_t stream) {
    const float* pred = (const float*)d_in[0];
    const int*   tgt  = (const int*)d_in[1];
    float* out = (float*)d_out;

    // workspace layout — 22.1 MB (26 MB proven safe)
    double* acc = (double*)d_ws;                       // 480 doubles
    float* U  = (float*)(acc + 480);                   // [4,512,512]      4 MB
    float* X1 = U + (size_t)NB * HW0;                  // [48,256,256]    12 MB
    unsigned short* Y1 = (unsigned short*)(X1 + (size_t)BC * 65536);  // 6 MB

    k_prep<<<1024, 256, 0, stream>>>(pred, tgt, U, X1, Y1, acc);

    k_main<<<16368, 256, 0, stream>>>(pred, U, tgt, X1, Y1, acc);

    k_final<<<1, 64, 0, stream>>>(acc, out);
}